// Round 8
// baseline (314.405 us; speedup 1.0000x reference)
//
#include <hip/hip_runtime.h>
#include <hip/hip_bf16.h>

// LinearAttention collapse (all I/O fp32; x->bf16 only inside the MFMA GEMM):
//   out[b] = x[b] @ W_eff[b] + b_eff[b]
//   W_eff[b] = Wq@Wo + Wk@(diag(aw[b]) * (Wp@Wo))          [256 x 64]
//   b_eff[b] = (bq+bp)@Wo + bo + bk@(diag(aw[b])*(Wp@Wo))  [64]
//   aw[b]    = s_x[b]@Wq + t_sum[b]*bq                     [512]
//   s_x[b]   = sum_n t[b,n]*x[b,n,:],  t_sum[b] = sum_n t[b,n]
//   t[b,n]   = SCALE*(x[b,n].(Wq@qw) + bq.qw)
//
// R8 = R7 resubmitted verbatim (R7 failed on container infra, no data).
// Probe: k_out is idempotent -> launched TWICE; out_warm ≈ dur - 301 - 2.
// Decode: ~325-332 -> k_out clean, attack phase1 next;
//         >=353    -> k_out is the hidden sink, rewrite its pipeline;
//         ~310-315 -> k_out L3-warm-fast, cold k_out ~21-26 confirmed.

#define NN 16384
#define CC 256
#define DD 512
#define HH 64
#define SCALE_F 0.125f

// float-offset workspace layout
#define OFF_SX    0        // [8][256]
#define OFF_TSUM  2048     // [8]
#define OFF_WQQ   2056     // [256]
#define OFF_BQQ   2312     // [1]
#define OFF_WPWO  2320     // [512][64] fp32
#define OFF_WQWO  35088    // [256][64] fp32
#define OFF_CBIAS 51472    // [64]
#define OFF_BEFF  51536    // [8][64]
#define OFF_WEFFT 52048    // bf16 [8][64][256] (byte ofs 208192, 16B aligned)
#define OFF_AW    117584   // [8][512] fp32

typedef unsigned short ushort_t;
typedef __attribute__((ext_vector_type(8))) short short8;     // 8 bf16
typedef __attribute__((ext_vector_type(4))) float floatx4;

__device__ __forceinline__ unsigned short f2bf(float f) {
    __hip_bfloat16 h = __float2bfloat16(f);
    return __builtin_bit_cast(unsigned short, h);
}

// ---------------- K0: batch-independent weight folding + zero accumulators ----
// grid 195: 0..127 WpWo (4 rows ea), 128..191 WqWo (4 rows ea),
//           192 wqq/bqq, 193 cbias, 194 zero s_x/t_sum
__global__ __launch_bounds__(256) void k_prep(
    const float* __restrict__ Wq, const float* __restrict__ bq,
    const float* __restrict__ qw, const float* __restrict__ Wp,
    const float* __restrict__ bp, const float* __restrict__ Wo,
    const float* __restrict__ bo, float* __restrict__ ws)
{
    __shared__ float lds[2056];
    const int tid = threadIdx.x;
    const int bid = blockIdx.x;

    if (bid < 128) {
        const int d0 = bid * 4;
        for (int i = tid; i < 2048; i += 256) lds[i] = Wp[d0 * 512 + i];
        __syncthreads();
        const int dl = tid >> 6, h = tid & 63;
        float acc = 0.f;
        for (int e = 0; e < 512; ++e)
            acc = fmaf(lds[dl * 512 + e], Wo[e * 64 + h], acc);
        ws[OFF_WPWO + (d0 + dl) * 64 + h] = acc;
    } else if (bid < 192) {
        const int c0 = (bid - 128) * 4;
        for (int i = tid; i < 2048; i += 256) lds[i] = Wq[c0 * 512 + i];
        __syncthreads();
        const int cl = tid >> 6, h = tid & 63;
        float acc = 0.f;
        for (int e = 0; e < 512; ++e)
            acc = fmaf(lds[cl * 512 + e], Wo[e * 64 + h], acc);
        ws[OFF_WQWO + (c0 + cl) * 64 + h] = acc;
    } else if (bid == 192) {
        // wqq = Wq @ qw ; bqq = bq . qw (wave-reduced)
        float* lb = lds + 2048;
        for (int i = tid; i < 512; i += 256) lds[i] = qw[i];
        if (tid == 0) *lb = 0.f;
        __syncthreads();
        const float* wr = Wq + tid * 512;
        float acc = 0.f;
        for (int d = 0; d < 512; ++d) acc = fmaf(wr[d], lds[d], acc);
        ws[OFF_WQQ + tid] = acc;
        float pb = fmaf(bq[tid], lds[tid], bq[tid + 256] * lds[tid + 256]);
#pragma unroll
        for (int m = 1; m < 64; m <<= 1) pb += __shfl_xor(pb, m);
        if ((tid & 63) == 0) atomicAdd(lb, pb);
        __syncthreads();
        if (tid == 0) ws[OFF_BQQ] = *lb;
    } else if (bid == 193) {
        // cbias[h] = (bq+bp)@Wo + bo ; 4 partials per h, LDS-reduced
        const int h = tid & 63, part = tid >> 6;
        float acc = 0.f;
        for (int d = part * 128; d < part * 128 + 128; ++d)
            acc = fmaf(bq[d] + bp[d], Wo[d * 64 + h], acc);
        lds[part * 64 + h] = acc;
        __syncthreads();
        if (tid < 64)
            ws[OFF_CBIAS + tid] = bo[tid] + lds[tid] + lds[64 + tid] +
                                  lds[128 + tid] + lds[192 + tid];
    } else {
        // zero s_x + t_sum
        for (int i = tid; i < 2056; i += 256) ws[OFF_SX + i] = 0.f;
    }
}

// ---------------- K1: stream x, reduce s_x / t_sum -----------------------
__global__ __launch_bounds__(256) void k_phase1(
    const float* __restrict__ x, float* __restrict__ ws)
{
    const int tid  = threadIdx.x;
    const int lane = tid & 63;
    const int wave = tid >> 6;
    const int quad = lane >> 4;
    const int l15  = lane & 15;
    __shared__ float lacc[256];
    __shared__ float ltsum;

    floatx4 wv[4];
#pragma unroll
    for (int j = 0; j < 4; ++j)
        wv[j] = *(const floatx4*)(ws + OFF_WQQ + j * 64 + l15 * 4);
    const float bqq = ws[OFF_BQQ];

    const int vb = blockIdx.x;
    const int b = vb >> 7;
    const int rbase = (vb & 127) * 128;
    lacc[tid] = 0.f;
    if (tid == 0) ltsum = 0.f;
    __syncthreads();

    const float* xb = x + (size_t)b * NN * CC;
    const int r0 = rbase + wave * 32 + quad;   // rows r0 + 4*it
    floatx4 accs[4];
#pragma unroll
    for (int j = 0; j < 4; ++j)
#pragma unroll
        for (int k = 0; k < 4; ++k) accs[j][k] = 0.f;
    float ts = 0.f;

#pragma unroll 2
    for (int it = 0; it < 8; ++it) {
        const float* xr = xb + (size_t)(r0 + it * 4) * CC + l15 * 4;
        const floatx4 x0 = *(const floatx4*)(xr);
        const floatx4 x1 = *(const floatx4*)(xr + 64);
        const floatx4 x2 = *(const floatx4*)(xr + 128);
        const floatx4 x3 = *(const floatx4*)(xr + 192);
        float p = 0.f;
#pragma unroll
        for (int k = 0; k < 4; ++k) {
            p = fmaf(x0[k], wv[0][k], p);
            p = fmaf(x1[k], wv[1][k], p);
            p = fmaf(x2[k], wv[2][k], p);
            p = fmaf(x3[k], wv[3][k], p);
        }
        p += __shfl_xor(p, 1);
        p += __shfl_xor(p, 2);
        p += __shfl_xor(p, 4);
        p += __shfl_xor(p, 8);
        const float t = SCALE_F * (p + bqq);
        ts += t;
#pragma unroll
        for (int k = 0; k < 4; ++k) {
            accs[0][k] = fmaf(t, x0[k], accs[0][k]);
            accs[1][k] = fmaf(t, x1[k], accs[1][k]);
            accs[2][k] = fmaf(t, x2[k], accs[2][k]);
            accs[3][k] = fmaf(t, x3[k], accs[3][k]);
        }
    }

#pragma unroll
    for (int j = 0; j < 4; ++j)
#pragma unroll
        for (int k = 0; k < 4; ++k) {
            float v = accs[j][k];
            v += __shfl_xor(v, 16);
            v += __shfl_xor(v, 32);
            if (quad == 0) atomicAdd(&lacc[j * 64 + l15 * 4 + k], v);
        }
    if (l15 == 0) atomicAdd(&ltsum, ts);
    __syncthreads();
    atomicAdd(&ws[OFF_SX + b * 256 + tid], lacc[tid]);
    if (tid == 0) atomicAdd(&ws[OFF_TSUM + b], ltsum);
}

// ---------------- K2a: aw[b,d] = s_x[b]@Wq[:,d] + tsum[b]*bq[d] ------------
// grid (8, 8). Idempotent.
__global__ __launch_bounds__(256) void k_aw(
    const float* __restrict__ Wq, const float* __restrict__ bq,
    float* __restrict__ ws)
{
    const int tid = threadIdx.x;
    const int b = blockIdx.y;
    const int dl = tid & 63, part = tid >> 6;
    const int d = blockIdx.x * 64 + dl;
    __shared__ float lsx[256];
    __shared__ float lred[256];
    __shared__ float lts;
    lsx[tid] = ws[OFF_SX + b * 256 + tid];
    if (tid == 0) lts = ws[OFF_TSUM + b];
    __syncthreads();

    const int c0 = part * 64;
    float a0 = 0.f, a1 = 0.f, a2 = 0.f, a3 = 0.f;
    for (int c = c0; c < c0 + 64; c += 4) {
        a0 = fmaf(lsx[c + 0], Wq[(c + 0) * 512 + d], a0);
        a1 = fmaf(lsx[c + 1], Wq[(c + 1) * 512 + d], a1);
        a2 = fmaf(lsx[c + 2], Wq[(c + 2) * 512 + d], a2);
        a3 = fmaf(lsx[c + 3], Wq[(c + 3) * 512 + d], a3);
    }
    lred[tid] = ((a0 + a1) + (a2 + a3));
    __syncthreads();
    if (tid < 64) {
        const float s = lred[tid] + lred[64 + tid] + lred[128 + tid] + lred[192 + tid];
        const int dd = blockIdx.x * 64 + tid;
        ws[OFF_AW + b * 512 + dd] = lts * bq[dd] + s;
    }
}

// ---------------- K2b: W_effT (bf16) + b_eff -- h-vectorized v2 ------------
// grid (256, 8): blockIdx.x = c, blockIdx.y = batch. Idempotent.
__global__ __launch_bounds__(256) void k_weff(
    const float* __restrict__ Wk, const float* __restrict__ bk,
    float* __restrict__ ws)
{
    const int tid = threadIdx.x;
    const int b = blockIdx.y;
    const int c = blockIdx.x;
    const int hq = tid & 15;
    const int part = tid >> 4;
    __shared__ floatx4 lr[256];
    __shared__ floatx4 lrb[256];

    const float* law = ws + OFF_AW + (size_t)b * 512;
    const float* wkr = Wk + (size_t)c * 512;
    const floatx4* wp4 = (const floatx4*)(ws + OFF_WPWO);
    const bool do_beff = (c == 0);

    floatx4 acc;
    acc[0] = acc[1] = acc[2] = acc[3] = 0.f;
    const int d0 = part * 32;
    for (int d = d0; d < d0 + 32; ++d) {
        const float g = wkr[d] * law[d];
        const floatx4 w = wp4[d * 16 + hq];
        acc[0] = fmaf(g, w[0], acc[0]);
        acc[1] = fmaf(g, w[1], acc[1]);
        acc[2] = fmaf(g, w[2], acc[2]);
        acc[3] = fmaf(g, w[3], acc[3]);
    }
    lr[tid] = acc;

    if (do_beff) {
        floatx4 bacc;
        bacc[0] = bacc[1] = bacc[2] = bacc[3] = 0.f;
        for (int d = d0; d < d0 + 32; ++d) {
            const float gb = bk[d] * law[d];
            const floatx4 w = wp4[d * 16 + hq];
            bacc[0] = fmaf(gb, w[0], bacc[0]);
            bacc[1] = fmaf(gb, w[1], bacc[1]);
            bacc[2] = fmaf(gb, w[2], bacc[2]);
            bacc[3] = fmaf(gb, w[3], bacc[3]);
        }
        lrb[tid] = bacc;
    }
    __syncthreads();

#pragma unroll
    for (int s = 8; s >= 1; s >>= 1) {
        if (part < s) {
            lr[tid] += lr[tid + s * 16];
            if (do_beff) lrb[tid] += lrb[tid + s * 16];
        }
        __syncthreads();
    }

    if (tid < 16) {
        const floatx4 wq = *(const floatx4*)(ws + OFF_WQWO + c * 64 + tid * 4);
        const floatx4 v = lr[tid];
        ushort_t* wt = (ushort_t*)(ws + OFF_WEFFT) + (size_t)b * (HH * CC);
        wt[(size_t)(tid * 4 + 0) * CC + c] = f2bf(wq[0] + v[0]);
        wt[(size_t)(tid * 4 + 1) * CC + c] = f2bf(wq[1] + v[1]);
        wt[(size_t)(tid * 4 + 2) * CC + c] = f2bf(wq[2] + v[2]);
        wt[(size_t)(tid * 4 + 3) * CC + c] = f2bf(wq[3] + v[3]);
        if (do_beff) {
            const floatx4 cb = *(const floatx4*)(ws + OFF_CBIAS + tid * 4);
            const floatx4 vb = lrb[tid];
            *(floatx4*)(ws + OFF_BEFF + b * 64 + tid * 4) = cb + vb;
        }
    }
}

// ---------------- K3: out = x @ W_eff + b_eff  (MFMA bf16) -----------------
// grid 1024. IDEMPOTENT (pure fn of x, ws -> out): launched TWICE this round
// to measure its true duration via Δdur (out_warm ≈ dur - 301 - 2).
__global__ __launch_bounds__(256) void k_out(
    const float* __restrict__ x, const float* __restrict__ ws,
    float* __restrict__ out)
{
    const int tid  = threadIdx.x;
    const int lane = tid & 63;
    const int wave = tid >> 6;
    const int quad = lane >> 4;
    const int l15  = lane & 15;
    __shared__ __align__(16) ushort_t lwt[64 * 264];

    const int vb = blockIdx.x;
    const int b = vb >> 7;
    const int rt0 = vb & 127;
    const ushort_t* wt = (const ushort_t*)(ws + OFF_WEFFT) + (size_t)b * (HH * CC);
    for (int o = tid; o < 2048; o += 256) {
        const int h = o >> 5, seg = o & 31;
        *(short8*)(lwt + h * 264 + seg * 8) = *(const short8*)(wt + h * 256 + seg * 8);
    }
    __syncthreads();

    const float* beff = ws + OFF_BEFF + b * 64;
    float bias[4];
#pragma unroll
    for (int ht = 0; ht < 4; ++ht) bias[ht] = beff[ht * 16 + l15];

#pragma unroll
    for (int s = 0; s < 2; ++s) {
        const int row0 = (rt0 + s * 128) * 64 + wave * 16;
        const float* xr = x + ((size_t)b * NN + row0 + l15) * CC + quad * 8;
        short8 afrag[8];
#pragma unroll
        for (int kk = 0; kk < 8; ++kk) {
            const floatx4 u0 = *(const floatx4*)(xr + kk * 32);
            const floatx4 u1 = *(const floatx4*)(xr + kk * 32 + 4);
            short8 t;
            t[0] = (short)f2bf(u0[0]); t[1] = (short)f2bf(u0[1]);
            t[2] = (short)f2bf(u0[2]); t[3] = (short)f2bf(u0[3]);
            t[4] = (short)f2bf(u1[0]); t[5] = (short)f2bf(u1[1]);
            t[6] = (short)f2bf(u1[2]); t[7] = (short)f2bf(u1[3]);
            afrag[kk] = t;
        }
        floatx4 acc[4];
#pragma unroll
        for (int ht = 0; ht < 4; ++ht)
#pragma unroll
            for (int r = 0; r < 4; ++r) acc[ht][r] = 0.f;

#pragma unroll
        for (int kk = 0; kk < 8; ++kk)
#pragma unroll
            for (int ht = 0; ht < 4; ++ht) {
                const short8 bf =
                    *(const short8*)(lwt + (ht * 16 + l15) * 264 + quad * 8 + kk * 32);
                acc[ht] = __builtin_amdgcn_mfma_f32_16x16x32_bf16(
                    afrag[kk], bf, acc[ht], 0, 0, 0);
            }

#pragma unroll
        for (int ht = 0; ht < 4; ++ht) {
            const int h = ht * 16 + l15;
#pragma unroll
            for (int r = 0; r < 4; ++r) {
                const int row = row0 + quad * 4 + r;
                out[((size_t)b * NN + row) * HH + h] = acc[ht][r] + bias[ht];
            }
        }
    }
}

extern "C" void kernel_launch(void* const* d_in, const int* in_sizes, int n_in,
                              void* d_out, int out_size, void* d_ws, size_t ws_size,
                              hipStream_t stream) {
    const float* x  = (const float*)d_in[0];
    const float* Wq = (const float*)d_in[1];
    const float* bq = (const float*)d_in[2];
    const float* Wk = (const float*)d_in[3];
    const float* bk = (const float*)d_in[4];
    const float* qw = (const float*)d_in[5];
    const float* Wp = (const float*)d_in[6];
    const float* bp = (const float*)d_in[7];
    const float* Wo = (const float*)d_in[8];
    const float* bo = (const float*)d_in[9];
    float* ws  = (float*)d_ws;
    float* out = (float*)d_out;

    hipLaunchKernelGGL(k_prep,   dim3(195),    dim3(256), 0, stream,
                       Wq, bq, qw, Wp, bp, Wo, bo, ws);
    hipLaunchKernelGGL(k_phase1, dim3(1024),   dim3(256), 0, stream, x, ws);
    hipLaunchKernelGGL(k_aw,     dim3(8, 8),   dim3(256), 0, stream, Wq, bq, ws);
    hipLaunchKernelGGL(k_weff,   dim3(256, 8), dim3(256), 0, stream, Wk, bk, ws);
    // k_out is idempotent: second launch measures its true cost via Δdur
    // (out_warm ≈ dur - 301 - 2; next round drops the duplicate)
    hipLaunchKernelGGL(k_out,    dim3(1024),   dim3(256), 0, stream, x, ws, out);
    hipLaunchKernelGGL(k_out,    dim3(1024),   dim3(256), 0, stream, x, ws, out);
}

// Round 9
// 290.206 us; speedup vs baseline: 1.0834x; 1.0834x over previous
//
#include <hip/hip_runtime.h>
#include <hip/hip_bf16.h>

// LinearAttention collapse (all I/O fp32; x->bf16 only inside the MFMA GEMM):
//   out[b] = x[b] @ W_eff[b] + b_eff[b]
//   W_eff[b] = Wq@Wo + Wk@(diag(aw[b]) * (Wp@Wo))          [256 x 64]
//   b_eff[b] = (bq+bp)@Wo + bo + bk@(diag(aw[b])*(Wp@Wo))  [64]
//   aw[b]    = s_x[b]@Wq + t_sum[b]*bq                     [512]
//   s_x[b]   = sum_n t[b,n]*x[b,n,:],  t_sum[b] = sum_n t[b,n]
//   t[b,n]   = SCALE*(x[b,n].(Wq@qw) + bq.qw)
//
// R9: ledger closed. R8 probe: k_out marginal ~12us (L3-warm floor). The
//     "missing 70-90us" = the harness reset tail (dozens of tiny memset/
//     restore dispatches below top-5 cutoff) -- fixed cost, not ours.
//     Controllable remainder: phase1 (model band 21-40us).
//   - k_out probe duplicate dropped (banked -13us)
//   - phase1: explicit 4-deep load batching (16KB/wave in flight before
//     the shfl chain) -> decouples load issue from the dependent reduce
//   - all other kernels byte-identical to R8 (proven)
// Decode: dur 287-292 -> phase1 was BW-saturated; controllable floor hit.
//         dur <=282   -> phase1 issue-throttle confirmed fixed.

#define NN 16384
#define CC 256
#define DD 512
#define HH 64
#define SCALE_F 0.125f

// float-offset workspace layout
#define OFF_SX    0        // [8][256]
#define OFF_TSUM  2048     // [8]
#define OFF_WQQ   2056     // [256]
#define OFF_BQQ   2312     // [1]
#define OFF_WPWO  2320     // [512][64] fp32
#define OFF_WQWO  35088    // [256][64] fp32
#define OFF_CBIAS 51472    // [64]
#define OFF_BEFF  51536    // [8][64]
#define OFF_WEFFT 52048    // bf16 [8][64][256] (byte ofs 208192, 16B aligned)
#define OFF_AW    117584   // [8][512] fp32

typedef unsigned short ushort_t;
typedef __attribute__((ext_vector_type(8))) short short8;     // 8 bf16
typedef __attribute__((ext_vector_type(4))) float floatx4;

__device__ __forceinline__ unsigned short f2bf(float f) {
    __hip_bfloat16 h = __float2bfloat16(f);
    return __builtin_bit_cast(unsigned short, h);
}

// ---------------- K0: batch-independent weight folding + zero accumulators ----
// grid 195: 0..127 WpWo (4 rows ea), 128..191 WqWo (4 rows ea),
//           192 wqq/bqq, 193 cbias, 194 zero s_x/t_sum
__global__ __launch_bounds__(256) void k_prep(
    const float* __restrict__ Wq, const float* __restrict__ bq,
    const float* __restrict__ qw, const float* __restrict__ Wp,
    const float* __restrict__ bp, const float* __restrict__ Wo,
    const float* __restrict__ bo, float* __restrict__ ws)
{
    __shared__ float lds[2056];
    const int tid = threadIdx.x;
    const int bid = blockIdx.x;

    if (bid < 128) {
        const int d0 = bid * 4;
        for (int i = tid; i < 2048; i += 256) lds[i] = Wp[d0 * 512 + i];
        __syncthreads();
        const int dl = tid >> 6, h = tid & 63;
        float acc = 0.f;
        for (int e = 0; e < 512; ++e)
            acc = fmaf(lds[dl * 512 + e], Wo[e * 64 + h], acc);
        ws[OFF_WPWO + (d0 + dl) * 64 + h] = acc;
    } else if (bid < 192) {
        const int c0 = (bid - 128) * 4;
        for (int i = tid; i < 2048; i += 256) lds[i] = Wq[c0 * 512 + i];
        __syncthreads();
        const int cl = tid >> 6, h = tid & 63;
        float acc = 0.f;
        for (int e = 0; e < 512; ++e)
            acc = fmaf(lds[cl * 512 + e], Wo[e * 64 + h], acc);
        ws[OFF_WQWO + (c0 + cl) * 64 + h] = acc;
    } else if (bid == 192) {
        // wqq = Wq @ qw ; bqq = bq . qw (wave-reduced)
        float* lb = lds + 2048;
        for (int i = tid; i < 512; i += 256) lds[i] = qw[i];
        if (tid == 0) *lb = 0.f;
        __syncthreads();
        const float* wr = Wq + tid * 512;
        float acc = 0.f;
        for (int d = 0; d < 512; ++d) acc = fmaf(wr[d], lds[d], acc);
        ws[OFF_WQQ + tid] = acc;
        float pb = fmaf(bq[tid], lds[tid], bq[tid + 256] * lds[tid + 256]);
#pragma unroll
        for (int m = 1; m < 64; m <<= 1) pb += __shfl_xor(pb, m);
        if ((tid & 63) == 0) atomicAdd(lb, pb);
        __syncthreads();
        if (tid == 0) ws[OFF_BQQ] = *lb;
    } else if (bid == 193) {
        // cbias[h] = (bq+bp)@Wo + bo ; 4 partials per h, LDS-reduced
        const int h = tid & 63, part = tid >> 6;
        float acc = 0.f;
        for (int d = part * 128; d < part * 128 + 128; ++d)
            acc = fmaf(bq[d] + bp[d], Wo[d * 64 + h], acc);
        lds[part * 64 + h] = acc;
        __syncthreads();
        if (tid < 64)
            ws[OFF_CBIAS + tid] = bo[tid] + lds[tid] + lds[64 + tid] +
                                  lds[128 + tid] + lds[192 + tid];
    } else {
        // zero s_x + t_sum
        for (int i = tid; i < 2056; i += 256) ws[OFF_SX + i] = 0.f;
    }
}

// ---------------- K1: stream x, reduce s_x / t_sum -----------------------
// 16-lane groups; 4-deep load batching: 16 floatx4 (16KB/wave) issued before
// the dependent shfl/FMA chains consume them.
__global__ __launch_bounds__(256) void k_phase1(
    const float* __restrict__ x, float* __restrict__ ws)
{
    const int tid  = threadIdx.x;
    const int lane = tid & 63;
    const int wave = tid >> 6;
    const int quad = lane >> 4;
    const int l15  = lane & 15;
    __shared__ float lacc[256];
    __shared__ float ltsum;

    floatx4 wv[4];
#pragma unroll
    for (int j = 0; j < 4; ++j)
        wv[j] = *(const floatx4*)(ws + OFF_WQQ + j * 64 + l15 * 4);
    const float bqq = ws[OFF_BQQ];

    const int vb = blockIdx.x;
    const int b = vb >> 7;
    const int rbase = (vb & 127) * 128;
    lacc[tid] = 0.f;
    if (tid == 0) ltsum = 0.f;
    __syncthreads();

    const float* xb = x + (size_t)b * NN * CC;
    const int r0 = rbase + wave * 32 + quad;   // rows r0 + 4*s, two batches
    floatx4 accs[4];
#pragma unroll
    for (int j = 0; j < 4; ++j)
#pragma unroll
        for (int k = 0; k < 4; ++k) accs[j][k] = 0.f;
    float ts = 0.f;

#pragma unroll
    for (int ib = 0; ib < 2; ++ib) {
        // ---- batch-load 4 sub-iterations (rows r0 + (ib*4+s)*4) ----
        floatx4 xs[4][4];
#pragma unroll
        for (int s = 0; s < 4; ++s) {
            const float* xr = xb + (size_t)(r0 + (ib * 4 + s) * 4) * CC + l15 * 4;
            xs[s][0] = *(const floatx4*)(xr);
            xs[s][1] = *(const floatx4*)(xr + 64);
            xs[s][2] = *(const floatx4*)(xr + 128);
            xs[s][3] = *(const floatx4*)(xr + 192);
        }
        // ---- compute 4 sub-iterations ----
#pragma unroll
        for (int s = 0; s < 4; ++s) {
            float p = 0.f;
#pragma unroll
            for (int k = 0; k < 4; ++k) {
                p = fmaf(xs[s][0][k], wv[0][k], p);
                p = fmaf(xs[s][1][k], wv[1][k], p);
                p = fmaf(xs[s][2][k], wv[2][k], p);
                p = fmaf(xs[s][3][k], wv[3][k], p);
            }
            p += __shfl_xor(p, 1);
            p += __shfl_xor(p, 2);
            p += __shfl_xor(p, 4);
            p += __shfl_xor(p, 8);
            const float t = SCALE_F * (p + bqq);
            ts += t;
#pragma unroll
            for (int k = 0; k < 4; ++k) {
                accs[0][k] = fmaf(t, xs[s][0][k], accs[0][k]);
                accs[1][k] = fmaf(t, xs[s][1][k], accs[1][k]);
                accs[2][k] = fmaf(t, xs[s][2][k], accs[2][k]);
                accs[3][k] = fmaf(t, xs[s][3][k], accs[3][k]);
            }
        }
    }

    // cross-quad reduce (xor 16, 32), quad0 lanes accumulate into LDS
#pragma unroll
    for (int j = 0; j < 4; ++j)
#pragma unroll
        for (int k = 0; k < 4; ++k) {
            float v = accs[j][k];
            v += __shfl_xor(v, 16);
            v += __shfl_xor(v, 32);
            if (quad == 0) atomicAdd(&lacc[j * 64 + l15 * 4 + k], v);
        }
    if (l15 == 0) atomicAdd(&ltsum, ts);
    __syncthreads();
    atomicAdd(&ws[OFF_SX + b * 256 + tid], lacc[tid]);
    if (tid == 0) atomicAdd(&ws[OFF_TSUM + b], ltsum);
}

// ---------------- K2a: aw[b,d] = s_x[b]@Wq[:,d] + tsum[b]*bq[d] ------------
// grid (8, 8).
__global__ __launch_bounds__(256) void k_aw(
    const float* __restrict__ Wq, const float* __restrict__ bq,
    float* __restrict__ ws)
{
    const int tid = threadIdx.x;
    const int b = blockIdx.y;
    const int dl = tid & 63, part = tid >> 6;
    const int d = blockIdx.x * 64 + dl;
    __shared__ float lsx[256];
    __shared__ float lred[256];
    __shared__ float lts;
    lsx[tid] = ws[OFF_SX + b * 256 + tid];
    if (tid == 0) lts = ws[OFF_TSUM + b];
    __syncthreads();

    const int c0 = part * 64;
    float a0 = 0.f, a1 = 0.f, a2 = 0.f, a3 = 0.f;
    for (int c = c0; c < c0 + 64; c += 4) {
        a0 = fmaf(lsx[c + 0], Wq[(c + 0) * 512 + d], a0);
        a1 = fmaf(lsx[c + 1], Wq[(c + 1) * 512 + d], a1);
        a2 = fmaf(lsx[c + 2], Wq[(c + 2) * 512 + d], a2);
        a3 = fmaf(lsx[c + 3], Wq[(c + 3) * 512 + d], a3);
    }
    lred[tid] = ((a0 + a1) + (a2 + a3));
    __syncthreads();
    if (tid < 64) {
        const float s = lred[tid] + lred[64 + tid] + lred[128 + tid] + lred[192 + tid];
        const int dd = blockIdx.x * 64 + tid;
        ws[OFF_AW + b * 512 + dd] = lts * bq[dd] + s;
    }
}

// ---------------- K2b: W_effT (bf16) + b_eff -- h-vectorized v2 ------------
// grid (256, 8): blockIdx.x = c, blockIdx.y = batch.
__global__ __launch_bounds__(256) void k_weff(
    const float* __restrict__ Wk, const float* __restrict__ bk,
    float* __restrict__ ws)
{
    const int tid = threadIdx.x;
    const int b = blockIdx.y;
    const int c = blockIdx.x;
    const int hq = tid & 15;
    const int part = tid >> 4;
    __shared__ floatx4 lr[256];
    __shared__ floatx4 lrb[256];

    const float* law = ws + OFF_AW + (size_t)b * 512;
    const float* wkr = Wk + (size_t)c * 512;
    const floatx4* wp4 = (const floatx4*)(ws + OFF_WPWO);
    const bool do_beff = (c == 0);

    floatx4 acc;
    acc[0] = acc[1] = acc[2] = acc[3] = 0.f;
    const int d0 = part * 32;
    for (int d = d0; d < d0 + 32; ++d) {
        const float g = wkr[d] * law[d];
        const floatx4 w = wp4[d * 16 + hq];
        acc[0] = fmaf(g, w[0], acc[0]);
        acc[1] = fmaf(g, w[1], acc[1]);
        acc[2] = fmaf(g, w[2], acc[2]);
        acc[3] = fmaf(g, w[3], acc[3]);
    }
    lr[tid] = acc;

    if (do_beff) {
        floatx4 bacc;
        bacc[0] = bacc[1] = bacc[2] = bacc[3] = 0.f;
        for (int d = d0; d < d0 + 32; ++d) {
            const float gb = bk[d] * law[d];
            const floatx4 w = wp4[d * 16 + hq];
            bacc[0] = fmaf(gb, w[0], bacc[0]);
            bacc[1] = fmaf(gb, w[1], bacc[1]);
            bacc[2] = fmaf(gb, w[2], bacc[2]);
            bacc[3] = fmaf(gb, w[3], bacc[3]);
        }
        lrb[tid] = bacc;
    }
    __syncthreads();

#pragma unroll
    for (int s = 8; s >= 1; s >>= 1) {
        if (part < s) {
            lr[tid] += lr[tid + s * 16];
            if (do_beff) lrb[tid] += lrb[tid + s * 16];
        }
        __syncthreads();
    }

    if (tid < 16) {
        const floatx4 wq = *(const floatx4*)(ws + OFF_WQWO + c * 64 + tid * 4);
        const floatx4 v = lr[tid];
        ushort_t* wt = (ushort_t*)(ws + OFF_WEFFT) + (size_t)b * (HH * CC);
        wt[(size_t)(tid * 4 + 0) * CC + c] = f2bf(wq[0] + v[0]);
        wt[(size_t)(tid * 4 + 1) * CC + c] = f2bf(wq[1] + v[1]);
        wt[(size_t)(tid * 4 + 2) * CC + c] = f2bf(wq[2] + v[2]);
        wt[(size_t)(tid * 4 + 3) * CC + c] = f2bf(wq[3] + v[3]);
        if (do_beff) {
            const floatx4 cb = *(const floatx4*)(ws + OFF_CBIAS + tid * 4);
            const floatx4 vb = lrb[tid];
            *(floatx4*)(ws + OFF_BEFF + b * 64 + tid * 4) = cb + vb;
        }
    }
}

// ---------------- K3: out = x @ W_eff + b_eff  (MFMA bf16) -----------------
// grid 1024: vb>>7 = batch, vb&127 = row-tile; TWO 64-row tiles per staging.
__global__ __launch_bounds__(256) void k_out(
    const float* __restrict__ x, const float* __restrict__ ws,
    float* __restrict__ out)
{
    const int tid  = threadIdx.x;
    const int lane = tid & 63;
    const int wave = tid >> 6;
    const int quad = lane >> 4;
    const int l15  = lane & 15;
    __shared__ __align__(16) ushort_t lwt[64 * 264];

    const int vb = blockIdx.x;
    const int b = vb >> 7;
    const int rt0 = vb & 127;
    const ushort_t* wt = (const ushort_t*)(ws + OFF_WEFFT) + (size_t)b * (HH * CC);
    for (int o = tid; o < 2048; o += 256) {
        const int h = o >> 5, seg = o & 31;
        *(short8*)(lwt + h * 264 + seg * 8) = *(const short8*)(wt + h * 256 + seg * 8);
    }
    __syncthreads();

    const float* beff = ws + OFF_BEFF + b * 64;
    float bias[4];
#pragma unroll
    for (int ht = 0; ht < 4; ++ht) bias[ht] = beff[ht * 16 + l15];

#pragma unroll
    for (int s = 0; s < 2; ++s) {
        const int row0 = (rt0 + s * 128) * 64 + wave * 16;
        const float* xr = x + ((size_t)b * NN + row0 + l15) * CC + quad * 8;
        short8 afrag[8];
#pragma unroll
        for (int kk = 0; kk < 8; ++kk) {
            const floatx4 u0 = *(const floatx4*)(xr + kk * 32);
            const floatx4 u1 = *(const floatx4*)(xr + kk * 32 + 4);
            short8 t;
            t[0] = (short)f2bf(u0[0]); t[1] = (short)f2bf(u0[1]);
            t[2] = (short)f2bf(u0[2]); t[3] = (short)f2bf(u0[3]);
            t[4] = (short)f2bf(u1[0]); t[5] = (short)f2bf(u1[1]);
            t[6] = (short)f2bf(u1[2]); t[7] = (short)f2bf(u1[3]);
            afrag[kk] = t;
        }
        floatx4 acc[4];
#pragma unroll
        for (int ht = 0; ht < 4; ++ht)
#pragma unroll
            for (int r = 0; r < 4; ++r) acc[ht][r] = 0.f;

#pragma unroll
        for (int kk = 0; kk < 8; ++kk)
#pragma unroll
            for (int ht = 0; ht < 4; ++ht) {
                const short8 bf =
                    *(const short8*)(lwt + (ht * 16 + l15) * 264 + quad * 8 + kk * 32);
                acc[ht] = __builtin_amdgcn_mfma_f32_16x16x32_bf16(
                    afrag[kk], bf, acc[ht], 0, 0, 0);
            }

#pragma unroll
        for (int ht = 0; ht < 4; ++ht) {
            const int h = ht * 16 + l15;
#pragma unroll
            for (int r = 0; r < 4; ++r) {
                const int row = row0 + quad * 4 + r;
                out[((size_t)b * NN + row) * HH + h] = acc[ht][r] + bias[ht];
            }
        }
    }
}

extern "C" void kernel_launch(void* const* d_in, const int* in_sizes, int n_in,
                              void* d_out, int out_size, void* d_ws, size_t ws_size,
                              hipStream_t stream) {
    const float* x  = (const float*)d_in[0];
    const float* Wq = (const float*)d_in[1];
    const float* bq = (const float*)d_in[2];
    const float* Wk = (const float*)d_in[3];
    const float* bk = (const float*)d_in[4];
    const float* qw = (const float*)d_in[5];
    const float* Wp = (const float*)d_in[6];
    const float* bp = (const float*)d_in[7];
    const float* Wo = (const float*)d_in[8];
    const float* bo = (const float*)d_in[9];
    float* ws  = (float*)d_ws;
    float* out = (float*)d_out;

    hipLaunchKernelGGL(k_prep,   dim3(195),    dim3(256), 0, stream,
                       Wq, bq, qw, Wp, bp, Wo, bo, ws);
    hipLaunchKernelGGL(k_phase1, dim3(1024),   dim3(256), 0, stream, x, ws);
    hipLaunchKernelGGL(k_aw,     dim3(8, 8),   dim3(256), 0, stream, Wq, bq, ws);
    hipLaunchKernelGGL(k_weff,   dim3(256, 8), dim3(256), 0, stream, Wk, bk, ws);
    hipLaunchKernelGGL(k_out,    dim3(1024),   dim3(256), 0, stream, x, ws, out);
}